// Round 7
// baseline (81.078 us; speedup 1.0000x reference)
//
#include <hip/hip_runtime.h>
#include <math.h>

typedef _Float16 half8 __attribute__((ext_vector_type(8)));
typedef float f32x4 __attribute__((ext_vector_type(4)));

#define RLT (1.0f/0.07f)

// out layout (flat fp32):
//   A      [256,196]  @ 0
//   logits [256,258]  @ 50176
//   Pos    [256,196]  @ 116224
//   Neg    [256,196]  @ 166400
//   A0_ref [256,256]  @ 216576

// aud_pk layout: [c>>3][m][c&7] fp16 — 64 groups x 256 m x 8 halves (16B per (cg,m))
__global__ __launch_bounds__(256) void prep_aud_pk(const float* __restrict__ aud,
                                                   _Float16* __restrict__ aud_pk) {
    int m = blockIdx.x, t = threadIdx.x;
    float a0 = aud[m * 512 + t];
    float a1 = aud[m * 512 + 256 + t];
    float s = a0 * a0 + a1 * a1;
    #pragma unroll
    for (int off = 32; off; off >>= 1) s += __shfl_down(s, off, 64);
    __shared__ float wsum[4];
    __shared__ float rns;
    if ((t & 63) == 0) wsum[t >> 6] = s;
    __syncthreads();
    if (t == 0) rns = 1.0f / fmaxf(sqrtf(wsum[0] + wsum[1] + wsum[2] + wsum[3]), 1e-12f);
    __syncthreads();
    float rn = rns;
    int c0 = t, c1 = t + 256;
    aud_pk[(c0 >> 3) * 2048 + m * 8 + (c0 & 7)] = (_Float16)(a0 * rn);
    aud_pk[(c1 >> 3) * 2048 + m * 8 + (c1 & 7)] = (_Float16)(a1 * rn);
}

// One block per (n, hw-half). NO LDS / NO BARRIERS in the K-loop:
// A fragments: global->reg scalar loads (L1-resident slice, lanes coalesced over hw) + cvt.
// B fragments: global->reg b128 loads from L2-resident aud_pk.
__global__ __launch_bounds__(512, 4) void av_direct(const float* __restrict__ img,
                                                    const _Float16* __restrict__ aud_pk,
                                                    float* __restrict__ out,
                                                    float* __restrict__ pmax,
                                                    float* __restrict__ psw,
                                                    float* __restrict__ pswa,
                                                    float* __restrict__ pdiag) {
    const int bid = blockIdx.x;
    const int n = bid >> 1, half = bid & 1;
    const int tid = threadIdx.x;
    const int w = tid >> 6, l = tid & 63;
    const int q = w & 3;          // m-quarter: cols 64q..64q+63
    const int hg = w >> 2;        // hw-group: 0 -> rows 0..63 (4 tiles), 1 -> 64..111 (3 tiles)
    const int HT = hg ? 3 : 4;
    const int kk = l >> 4, lm = l & 15;

    __shared__ float rnorm_s[112];
    __shared__ float red_max[2][256], red_sw[2][256], red_swa[2][256];
    __shared__ float diag_parts[2][4][4];

    const float* imgn = img + (size_t)n * (512 * 196);

    // per-ht A row (this lane holds row lm of each 16-row tile); clamp invalid rows to row 0
    int hwh[4];
    #pragma unroll
    for (int ht = 0; ht < 4; ht++) {
        int row = hg * 64 + ht * 16 + lm;
        hwh[ht] = half * 98 + ((row < 98) ? row : 0);
    }

    // per-lane B base (halves): aud_pk[(kk)][q*64+lm] chunk; +t*8192 per step, +mt*128 per m-tile
    const _Float16* bbase = aud_pk + ((size_t)(kk * 256 + q * 64 + lm) << 3);

    f32x4 acc[4][4];
    #pragma unroll
    for (int ht = 0; ht < 4; ht++)
        #pragma unroll
        for (int mt = 0; mt < 4; mt++)
            acc[ht][mt] = (f32x4){0.f, 0.f, 0.f, 0.f};

    float nrm[4] = {0.f, 0.f, 0.f, 0.f};

    for (int t = 0; t < 16; ++t) {
        half8 bfrag[4];
        #pragma unroll
        for (int mt = 0; mt < 4; mt++)
            bfrag[mt] = *(const half8*)(bbase + (size_t)t * 8192 + mt * 128);

        const float* srcc = imgn + (size_t)(32 * t + kk * 8) * 196;
        half8 af[4];
        #pragma unroll
        for (int ht = 0; ht < 4; ht++) {
            if (ht < HT) {
                float avv[8];
                #pragma unroll
                for (int i = 0; i < 8; i++) avv[i] = srcc[i * 196 + hwh[ht]];
                #pragma unroll
                for (int i = 0; i < 8; i++) {
                    af[ht][i] = (_Float16)avv[i];
                    nrm[ht] += avv[i] * avv[i];
                }
            }
        }
        #pragma unroll
        for (int ht = 0; ht < 4; ht++)
            if (ht < HT)
                #pragma unroll
                for (int mt = 0; mt < 4; mt++)
                    acc[ht][mt] = __builtin_amdgcn_mfma_f32_16x16x32_f16(
                        af[ht], bfrag[mt], acc[ht][mt], 0, 0, 0);
    }

    // ---- full row norms: lane covered 8 c/step for its rows; kk groups cover disjoint c
    if (tid >= 98 && tid < 112) rnorm_s[tid] = 0.f;   // pad rows (never written below)
    #pragma unroll
    for (int ht = 0; ht < 4; ht++) {
        float s = nrm[ht];
        s += __shfl_xor(s, 16, 64);
        s += __shfl_xor(s, 32, 64);
        if (q == 0 && l < 16 && ht < HT) {
            int row = hg * 64 + ht * 16 + lm;        // l<16 => kk==0, lm==l
            if (row < 98) rnorm_s[row] = 1.0f / fmaxf(sqrtf(s), 1e-12f);
        }
    }
    __syncthreads();

    // ---- fused epilogue
    float mx[4], sw[4], swa[4];
    #pragma unroll
    for (int mt = 0; mt < 4; mt++) { mx[mt] = -1e30f; sw[mt] = 0.f; swa[mt] = 0.f; }
    float s1n = 0.f, s1d = 0.f, s2n = 0.f, s2d = 0.f;
    const int dmt = (n >> 4) & 3, dq = n >> 6, dl = n & 15;
    const bool isdiag = (q == dq) && (lm == dl);

    #pragma unroll
    for (int ht = 0; ht < 4; ht++) {
        if (ht < HT) {
            int rowb = hg * 64 + ht * 16 + (kk << 2);
            #pragma unroll
            for (int r = 0; r < 4; r++) {
                int row = rowb + r;
                float rn = rnorm_s[row];
                bool valid = row < 98;
                int hw = half * 98 + row;
                #pragma unroll
                for (int mt = 0; mt < 4; mt++) {
                    float a0 = acc[ht][mt][r] * rn;
                    if (valid) {
                        float wg = 1.0f / (1.0f + __expf((0.65f - a0) * (1.0f / 0.03f)));
                        mx[mt]  = fmaxf(mx[mt], a0);
                        sw[mt] += wg;
                        swa[mt] += wg * a0;
                        if (isdiag && mt == dmt) {
                            out[n * 196 + hw] = a0;                 // A
                            out[116224 + n * 196 + hw] = wg;        // Pos
                            float p2 = 1.0f / (1.0f + __expf((0.40f - a0) * (1.0f / 0.03f)));
                            float ng = 1.0f - p2;
                            out[166400 + n * 196 + hw] = ng;        // Neg
                            s1n += wg * a0; s1d += wg;
                            s2n += ng * a0; s2d += ng;
                        }
                    }
                }
            }
        }
    }

    // cross-lane reduce (lane groups 16 apart hold same m, different rows)
    #pragma unroll
    for (int mt = 0; mt < 4; mt++) {
        float m1 = mx[mt], v1 = sw[mt], v2 = swa[mt];
        m1 = fmaxf(m1, __shfl_xor(m1, 16, 64)); v1 += __shfl_xor(v1, 16, 64); v2 += __shfl_xor(v2, 16, 64);
        m1 = fmaxf(m1, __shfl_xor(m1, 32, 64)); v1 += __shfl_xor(v1, 32, 64); v2 += __shfl_xor(v2, 32, 64);
        if (l < 16) {
            int m = q * 64 + mt * 16 + l;
            red_max[hg][m] = m1; red_sw[hg][m] = v1; red_swa[hg][m] = v2;
        }
    }
    if (isdiag) {
        diag_parts[hg][kk][0] = s1n;
        diag_parts[hg][kk][1] = s1d;
        diag_parts[hg][kk][2] = s2n;
        diag_parts[hg][kk][3] = s2d;
    }
    __syncthreads();

    // ---- write per-(n,half) partials to workspace
    if (tid < 256) {
        int m = tid;
        int base = (n * 2 + half) * 256 + m;
        pmax[base] = fmaxf(red_max[0][m], red_max[1][m]);
        psw[base]  = red_sw[0][m] + red_sw[1][m];
        pswa[base] = red_swa[0][m] + red_swa[1][m];
    }
    if (tid < 4) {
        float s = 0.f;
        #pragma unroll
        for (int h2 = 0; h2 < 2; h2++)
            #pragma unroll
            for (int lg = 0; lg < 4; lg++)
                s += diag_parts[h2][lg][tid];
        pdiag[(n * 2 + half) * 4 + tid] = s;
    }
}

__global__ __launch_bounds__(256) void av_final(const float* __restrict__ pmax,
                                                const float* __restrict__ psw,
                                                const float* __restrict__ pswa,
                                                const float* __restrict__ pdiag,
                                                float* __restrict__ out) {
    int n = blockIdx.x, m = threadIdx.x;
    int b0 = (n * 2) * 256 + m, b1 = (n * 2 + 1) * 256 + m;
    float mx = fmaxf(pmax[b0], pmax[b1]);
    float sim = (pswa[b0] + pswa[b1]) / (psw[b0] + psw[b1]);
    if (m == n) sim *= -99.0f;
    out[50176 + n * 258 + 1 + m] = sim * RLT;
    out[216576 + n * 256 + m] = mx;
    if (m == n) {
        const float* d = pdiag + n * 8;   // [half0: 4][half1: 4]
        out[50176 + n * 258]       = ((d[0] + d[4]) / (d[1] + d[5])) * RLT;
        out[50176 + n * 258 + 257] = ((d[2] + d[6]) / (d[3] + d[7])) * RLT;
    }
}

extern "C" void kernel_launch(void* const* d_in, const int* in_sizes, int n_in,
                              void* d_out, int out_size, void* d_ws, size_t ws_size,
                              hipStream_t stream) {
    const float* img = (const float*)d_in[0];
    const float* aud = (const float*)d_in[1];
    float* out = (float*)d_out;

    _Float16* aud_pk = (_Float16*)d_ws;          // 256 KB region reserved
    float* wsf   = (float*)d_ws;
    float* pmax  = wsf + 65536;                  // after aud_pk (262144 B)
    float* psw   = pmax + 131072;                // 256*2*256
    float* pswa  = psw + 131072;
    float* pdiag = pswa + 131072;                // 256*2*4

    prep_aud_pk<<<256, 256, 0, stream>>>(aud, aud_pk);
    av_direct<<<512, 512, 0, stream>>>(img, aud_pk, out, pmax, psw, pswa, pdiag);
    av_final<<<256, 256, 0, stream>>>(pmax, psw, pswa, pdiag, out);
}

// Round 8
// 55.007 us; speedup vs baseline: 1.4740x; 1.4740x over previous
//
#include <hip/hip_runtime.h>
#include <math.h>

typedef _Float16 half8 __attribute__((ext_vector_type(8)));
typedef float f32x4 __attribute__((ext_vector_type(4)));

#define RLT (1.0f/0.07f)

// out layout (flat fp32):
//   A      [256,196]  @ 0
//   logits [256,258]  @ 50176
//   Pos    [256,196]  @ 116224
//   Neg    [256,196]  @ 166400
//   A0_ref [256,256]  @ 216576

// aud_pk layout: [c>>3][m][c&7] fp16 — 64 groups x 256 m x 8 halves (16B per (cg,m))
__global__ __launch_bounds__(256) void prep_aud_pk(const float* __restrict__ aud,
                                                   _Float16* __restrict__ aud_pk) {
    int m = blockIdx.x, t = threadIdx.x;
    float a0 = aud[m * 512 + t];
    float a1 = aud[m * 512 + 256 + t];
    float s = a0 * a0 + a1 * a1;
    #pragma unroll
    for (int off = 32; off; off >>= 1) s += __shfl_down(s, off, 64);
    __shared__ float wsum[4];
    __shared__ float rns;
    if ((t & 63) == 0) wsum[t >> 6] = s;
    __syncthreads();
    if (t == 0) rns = 1.0f / fmaxf(sqrtf(wsum[0] + wsum[1] + wsum[2] + wsum[3]), 1e-12f);
    __syncthreads();
    float rn = rns;
    int c0 = t, c1 = t + 256;
    aud_pk[(c0 >> 3) * 2048 + m * 8 + (c0 & 7)] = (_Float16)(a0 * rn);
    aud_pk[(c1 >> 3) * 2048 + m * 8 + (c1 & 7)] = (_Float16)(a1 * rn);
}

// One block per (n, hw-half). 1 block/CU, 256 VGPR/wave budget (launch_bounds 512,2):
// acc=64 AGPR + deep reg prefetch with NO spills.
// A: 2-step-deep reg prefetch -> LDS dbuf. B: reg-staged (load top / ds_write bottom).
// No global_load_lds => barrier doesn't drain in-flight register loads.
__global__ __launch_bounds__(512, 2) void av_pipe(const float* __restrict__ img,
                                                  const _Float16* __restrict__ aud_pk,
                                                  float* __restrict__ out,
                                                  float* __restrict__ pmax,
                                                  float* __restrict__ psw,
                                                  float* __restrict__ pswa,
                                                  float* __restrict__ pdiag) {
    const int bid = blockIdx.x;
    const int n = bid >> 1, half = bid & 1;
    const int tid = threadIdx.x;
    const int w = tid >> 6, l = tid & 63;
    const int q = w & 3;          // m-quarter: cols 64q..64q+63
    const int hg = w >> 2;        // hw-group: 0 -> rows 0..63 (4 tiles), 1 -> 64..111 (3 tiles)
    const int HT = hg ? 3 : 4;

    __shared__ _Float16 __align__(16) Abuf[2][4][112][8];  // [buf][kg][row][j] 14.3 KB
    __shared__ _Float16 __align__(16) Bbuf[2][4][256][8];  // [buf][kg][m][j]   32 KB
    __shared__ float nrm_parts[4][98];
    __shared__ float rnorm_s[112];
    __shared__ float red_max[2][256], red_sw[2][256], red_swa[2][256];
    __shared__ float diag_parts[2][4][4];

    // zero the pad rows (98..111) of both A buffers once (never overwritten)
    if (tid < 112) {
        int b = tid / 56, rem = tid % 56, kg = rem / 14, row = 98 + rem % 14;
        *(float4*)&Abuf[b][kg][row][0] = make_float4(0.f, 0.f, 0.f, 0.f);
    }

    const float* imgn = img + (size_t)n * (512 * 196);
    const bool act = tid < 392;          // A-staging: fixed hw row, 8 consecutive c (one kg)
    const int p   = act ? tid / 98 : 0;  // kg within the 32-c step
    const int hwl = act ? tid % 98 : 0;  // local row
    const int g   = half * 98 + hwl;     // global hw
    float nrm = 0.f;
    float av0[8], av1[8];
    float4 bld0, bld1;

    const float4* audv = (const float4*)aud_pk;

    #define LOAD_A_TO(dst, t)                                                       \
        do {                                                                        \
            if (act) {                                                              \
                const float* src = imgn + ((size_t)(32 * (t) + p * 8)) * 196 + g;   \
                _Pragma("unroll")                                                   \
                for (int i = 0; i < 8; i++) dst[i] = src[i * 196];                  \
            }                                                                       \
        } while (0)

    #define STAGE_A_FROM(srcv, buf)                                                 \
        do {                                                                        \
            if (act) {                                                              \
                half8 h0;                                                           \
                _Pragma("unroll")                                                   \
                for (int i = 0; i < 8; i++) {                                       \
                    h0[i] = (_Float16)srcv[i];                                      \
                    nrm += srcv[i] * srcv[i];                                       \
                }                                                                   \
                *(half8*)&Abuf[buf][p][hwl][0] = h0;                                \
            }                                                                       \
        } while (0)

    #define LOAD_B(t)                                                               \
        do {                                                                        \
            bld0 = audv[(size_t)(t) * 1024 + tid];                                  \
            bld1 = audv[(size_t)(t) * 1024 + tid + 512];                            \
        } while (0)

    #define STAGE_B(buf)                                                            \
        do {                                                                        \
            ((float4*)&Bbuf[buf][0][0][0])[tid]       = bld0;                       \
            ((float4*)&Bbuf[buf][0][0][0])[tid + 512] = bld1;                       \
        } while (0)

    // ---- prologue: stage step 0 into buf 0, prefetch A(1)->av1, A(2)->av0
    LOAD_A_TO(av0, 0);
    LOAD_B(0);
    STAGE_A_FROM(av0, 0);
    STAGE_B(0);
    LOAD_A_TO(av1, 1);
    LOAD_A_TO(av0, 2);
    __syncthreads();

    f32x4 acc[4][4];
    #pragma unroll
    for (int ht = 0; ht < 4; ht++)
        #pragma unroll
        for (int mt = 0; mt < 4; mt++)
            acc[ht][mt] = (f32x4){0.f, 0.f, 0.f, 0.f};

    const int kk = l >> 4, lm = l & 15;
    // per-lane LDS fragment offsets (in halves)
    const int aoff = kk * 896  + (hg * 64 + lm) * 8;   // + ht*128
    const int boff = kk * 2048 + (q * 64 + lm) * 8;    // + mt*128

    // step t: load B(t+1) at top (L2 gap = full step), stage A(t+1) (loaded at t-2),
    //         load A(t+3) into freed slot, MFMA from buf cur, ds_write B late.
    #define STEP(t, cur, avS)                                                       \
        do {                                                                        \
            const int nb_ = (cur) ^ 1;                                              \
            if ((t) <= 14) LOAD_B((t) + 1);                                         \
            if ((t) <= 14) STAGE_A_FROM(avS, nb_);                                  \
            if ((t) <= 12) LOAD_A_TO(avS, (t) + 3);                                 \
            {                                                                       \
                const _Float16* Ab = &Abuf[cur][0][0][0];                           \
                const _Float16* Bb = &Bbuf[cur][0][0][0];                           \
                half8 afrag[4];                                                     \
                _Pragma("unroll")                                                   \
                for (int ht = 0; ht < 4; ht++)                                      \
                    if (ht < HT) afrag[ht] = *(const half8*)(Ab + aoff + ht * 128); \
                _Pragma("unroll")                                                   \
                for (int mt = 0; mt < 4; mt++) {                                    \
                    half8 bfrag = *(const half8*)(Bb + boff + mt * 128);            \
                    _Pragma("unroll")                                               \
                    for (int ht = 0; ht < 4; ht++)                                  \
                        if (ht < HT)                                                \
                            acc[ht][mt] = __builtin_amdgcn_mfma_f32_16x16x32_f16(   \
                                afrag[ht], bfrag, acc[ht][mt], 0, 0, 0);            \
                }                                                                   \
            }                                                                       \
            if ((t) <= 14) STAGE_B(nb_);                                            \
            __syncthreads();                                                        \
        } while (0)

    for (int tt = 0; tt < 16; tt += 2) {
        STEP(tt,     0, av1);
        STEP(tt + 1, 1, av0);
    }

    #undef STEP
    #undef LOAD_B
    #undef STAGE_B
    #undef LOAD_A_TO
    #undef STAGE_A_FROM

    // ---- img row norms (each row fully covered: 4 kg x 8 c x 16 steps)
    if (act) nrm_parts[p][hwl] = nrm;
    __syncthreads();
    if (tid < 112) {
        float v = 0.f;
        if (tid < 98)
            v = 1.0f / fmaxf(sqrtf(nrm_parts[0][tid] + nrm_parts[1][tid] +
                                   nrm_parts[2][tid] + nrm_parts[3][tid]), 1e-12f);
        rnorm_s[tid] = v;
    }
    __syncthreads();

    // ---- fused epilogue
    float mx[4], sw[4], swa[4];
    #pragma unroll
    for (int mt = 0; mt < 4; mt++) { mx[mt] = -1e30f; sw[mt] = 0.f; swa[mt] = 0.f; }
    float s1n = 0.f, s1d = 0.f, s2n = 0.f, s2d = 0.f;
    const int dmt = (n >> 4) & 3, dq = n >> 6, dl = n & 15;
    const bool isdiag = (q == dq) && (lm == dl);

    #pragma unroll
    for (int ht = 0; ht < 4; ht++) {
        if (ht < HT) {
            int rowb = hg * 64 + ht * 16 + (kk << 2);
            #pragma unroll
            for (int r = 0; r < 4; r++) {
                int row = rowb + r;
                float rn = rnorm_s[row];
                bool valid = row < 98;
                int hw = half * 98 + row;
                #pragma unroll
                for (int mt = 0; mt < 4; mt++) {
                    float a0 = acc[ht][mt][r] * rn;
                    if (valid) {
                        float wg = 1.0f / (1.0f + __expf((0.65f - a0) * (1.0f / 0.03f)));
                        mx[mt]  = fmaxf(mx[mt], a0);
                        sw[mt] += wg;
                        swa[mt] += wg * a0;
                        if (isdiag && mt == dmt) {
                            out[n * 196 + hw] = a0;                 // A
                            out[116224 + n * 196 + hw] = wg;        // Pos
                            float p2 = 1.0f / (1.0f + __expf((0.40f - a0) * (1.0f / 0.03f)));
                            float ng = 1.0f - p2;
                            out[166400 + n * 196 + hw] = ng;        // Neg
                            s1n += wg * a0; s1d += wg;
                            s2n += ng * a0; s2d += ng;
                        }
                    }
                }
            }
        }
    }

    // cross-lane reduce (lane groups 16 apart hold same m, different rows)
    #pragma unroll
    for (int mt = 0; mt < 4; mt++) {
        float m1 = mx[mt], v1 = sw[mt], v2 = swa[mt];
        m1 = fmaxf(m1, __shfl_xor(m1, 16, 64)); v1 += __shfl_xor(v1, 16, 64); v2 += __shfl_xor(v2, 16, 64);
        m1 = fmaxf(m1, __shfl_xor(m1, 32, 64)); v1 += __shfl_xor(v1, 32, 64); v2 += __shfl_xor(v2, 32, 64);
        if (l < 16) {
            int m = q * 64 + mt * 16 + l;
            red_max[hg][m] = m1; red_sw[hg][m] = v1; red_swa[hg][m] = v2;
        }
    }
    if (isdiag) {
        diag_parts[hg][kk][0] = s1n;
        diag_parts[hg][kk][1] = s1d;
        diag_parts[hg][kk][2] = s2n;
        diag_parts[hg][kk][3] = s2d;
    }
    __syncthreads();

    // ---- write per-(n,half) partials to workspace
    if (tid < 256) {
        int m = tid;
        int base = (n * 2 + half) * 256 + m;
        pmax[base] = fmaxf(red_max[0][m], red_max[1][m]);
        psw[base]  = red_sw[0][m] + red_sw[1][m];
        pswa[base] = red_swa[0][m] + red_swa[1][m];
    }
    if (tid < 4) {
        float s = 0.f;
        #pragma unroll
        for (int h2 = 0; h2 < 2; h2++)
            #pragma unroll
            for (int lg = 0; lg < 4; lg++)
                s += diag_parts[h2][lg][tid];
        pdiag[(n * 2 + half) * 4 + tid] = s;
    }
}

__global__ __launch_bounds__(256) void av_final(const float* __restrict__ pmax,
                                                const float* __restrict__ psw,
                                                const float* __restrict__ pswa,
                                                const float* __restrict__ pdiag,
                                                float* __restrict__ out) {
    int n = blockIdx.x, m = threadIdx.x;
    int b0 = (n * 2) * 256 + m, b1 = (n * 2 + 1) * 256 + m;
    float mx = fmaxf(pmax[b0], pmax[b1]);
    float sim = (pswa[b0] + pswa[b1]) / (psw[b0] + psw[b1]);
    if (m == n) sim *= -99.0f;
    out[50176 + n * 258 + 1 + m] = sim * RLT;
    out[216576 + n * 256 + m] = mx;
    if (m == n) {
        const float* d = pdiag + n * 8;   // [half0: 4][half1: 4]
        out[50176 + n * 258]       = ((d[0] + d[4]) / (d[1] + d[5])) * RLT;
        out[50176 + n * 258 + 257] = ((d[2] + d[6]) / (d[3] + d[7])) * RLT;
    }
}

extern "C" void kernel_launch(void* const* d_in, const int* in_sizes, int n_in,
                              void* d_out, int out_size, void* d_ws, size_t ws_size,
                              hipStream_t stream) {
    const float* img = (const float*)d_in[0];
    const float* aud = (const float*)d_in[1];
    float* out = (float*)d_out;

    _Float16* aud_pk = (_Float16*)d_ws;          // 256 KB region reserved
    float* wsf   = (float*)d_ws;
    float* pmax  = wsf + 65536;                  // after aud_pk (262144 B)
    float* psw   = pmax + 131072;                // 256*2*256
    float* pswa  = psw + 131072;
    float* pdiag = pswa + 131072;                // 256*2*4

    prep_aud_pk<<<256, 256, 0, stream>>>(aud, aud_pk);
    av_pipe<<<512, 512, 0, stream>>>(img, aud_pk, out, pmax, psw, pswa, pdiag);
    av_final<<<256, 256, 0, stream>>>(pmax, psw, pswa, pdiag, out);
}

// Round 9
// 43.873 us; speedup vs baseline: 1.8480x; 1.2538x over previous
//
#include <hip/hip_runtime.h>
#include <math.h>

typedef _Float16 half8 __attribute__((ext_vector_type(8)));
typedef float f32x4 __attribute__((ext_vector_type(4)));

#define RLT (1.0f/0.07f)

// out layout (flat fp32):
//   A      [256,196]  @ 0
//   logits [256,258]  @ 50176
//   Pos    [256,196]  @ 116224
//   Neg    [256,196]  @ 166400
//   A0_ref [256,256]  @ 216576

__device__ __forceinline__ void gll16(const void* g, void* l) {
    __builtin_amdgcn_global_load_lds(
        (const __attribute__((address_space(1))) void*)g,
        (__attribute__((address_space(3))) void*)l, 16, 0, 0);
}

// aud_pk layout: [c>>3][m][c&7] fp16 — 64 groups x 256 m x 8 halves (16B per (cg,m))
__global__ __launch_bounds__(256) void prep_aud_pk(const float* __restrict__ aud,
                                                   _Float16* __restrict__ aud_pk) {
    int m = blockIdx.x, t = threadIdx.x;
    float a0 = aud[m * 512 + t];
    float a1 = aud[m * 512 + 256 + t];
    float s = a0 * a0 + a1 * a1;
    #pragma unroll
    for (int off = 32; off; off >>= 1) s += __shfl_down(s, off, 64);
    __shared__ float wsum[4];
    __shared__ float rns;
    if ((t & 63) == 0) wsum[t >> 6] = s;
    __syncthreads();
    if (t == 0) rns = 1.0f / fmaxf(sqrtf(wsum[0] + wsum[1] + wsum[2] + wsum[3]), 1e-12f);
    __syncthreads();
    float rn = rns;
    int c0 = t, c1 = t + 256;
    aud_pk[(c0 >> 3) * 2048 + m * 8 + (c0 & 7)] = (_Float16)(a0 * rn);
    aud_pk[(c1 >> 3) * 2048 + m * 8 + (c1 & 7)] = (_Float16)(a1 * rn);
}

// One block per (n, hw-half). 2 blocks/CU (launch_bounds 512,4).
// B: global_load_lds double-buffer. A: 2-step reg prefetch -> cvt -> ds_write dbuf.
// K-loop uses RAW s_barrier with COUNTED vmcnt(8): B gll16s drained for cross-wave
// visibility, while the 8 newest vmem ops (next-next A loads) stay in flight
// across the barrier (T3/T4). Per-wave vmem issue counts kept uniform by having
// non-staging threads issue clamped dummy A-loads.
__global__ __launch_bounds__(512, 4) void av_cnt(const float* __restrict__ img,
                                                 const _Float16* __restrict__ aud_pk,
                                                 float* __restrict__ out,
                                                 float* __restrict__ pmax,
                                                 float* __restrict__ psw,
                                                 float* __restrict__ pswa,
                                                 float* __restrict__ pdiag) {
    const int bid = blockIdx.x;
    const int n = bid >> 1, half = bid & 1;
    const int tid = threadIdx.x;
    const int w = tid >> 6, l = tid & 63;
    const int q = w & 3;          // m-quarter: cols 64q..64q+63
    const int hg = w >> 2;        // hw-group: 0 -> rows 0..63 (4 tiles), 1 -> 64..111 (3 tiles)
    const int HT = hg ? 3 : 4;

    __shared__ _Float16 __align__(16) Abuf[2][4][112][8];  // [buf][kg][row][j] 14.3 KB
    __shared__ _Float16 __align__(16) Bbuf[2][4][256][8];  // [buf][kg][m][j]   32 KB
    __shared__ float nrm_parts[4][98];
    __shared__ float rnorm_s[112];
    __shared__ float red_max[2][256], red_sw[2][256], red_swa[2][256];
    __shared__ float diag_parts[2][4][4];

    // zero the pad rows (98..111) of both A buffers once (never overwritten)
    if (tid < 112) {
        int b = tid / 56, rem = tid % 56, kg = rem / 14, row = 98 + rem % 14;
        *(float4*)&Abuf[b][kg][row][0] = make_float4(0.f, 0.f, 0.f, 0.f);
    }

    const float* imgn = img + (size_t)n * (512 * 196);
    const bool act = tid < 392;              // A cvt/ds_write owners
    const int p   = act ? tid / 98 : 0;      // kg within the 32-c step (dummies use 0)
    const int hwl = act ? tid % 98 : 0;      // local row (dummies clamp to 0)
    const int g   = half * 98 + hwl;         // global hw
    float nrm = 0.f;
    float av0[8], av1[8];

    // ---- B stage via global_load_lds (2 per thread, uniform across all waves)
    #define STAGE_B(t, buf)                                                         \
        do {                                                                        \
            const _Float16* g0 = aud_pk + (((size_t)(t) * 1024 + w * 64 + l) << 3); \
            _Float16* l0 = &Bbuf[buf][0][0][0] + ((w * 64) << 3);                   \
            gll16(g0, l0);                                                          \
            gll16(g0 + 4096, l0 + 4096);                                            \
        } while (0)

    // ---- A loads: ALL threads issue 8 dwords (uniform vmcnt); dummies read row 0
    #define LOAD_A_TO(dst, t)                                                       \
        do {                                                                        \
            const float* src = imgn + ((size_t)(32 * (t) + p * 8)) * 196 + g;       \
            _Pragma("unroll")                                                       \
            for (int i = 0; i < 8; i++) dst[i] = src[i * 196];                      \
        } while (0)

    #define STAGE_A_FROM(srcv, buf)                                                 \
        do {                                                                        \
            if (act) {                                                              \
                half8 h0;                                                           \
                _Pragma("unroll")                                                   \
                for (int i = 0; i < 8; i++) {                                       \
                    h0[i] = (_Float16)srcv[i];                                      \
                    nrm += srcv[i] * srcv[i];                                       \
                }                                                                   \
                *(half8*)&Abuf[buf][p][hwl][0] = h0;                                \
            }                                                                       \
        } while (0)

    // ---- prologue: B(0) gll16, A(0)->av0, A(1)->av1, stage A(0), counted barrier
    STAGE_B(0, 0);
    asm volatile("" ::: "memory");
    LOAD_A_TO(av0, 0);
    asm volatile("" ::: "memory");
    LOAD_A_TO(av1, 1);
    asm volatile("" ::: "memory");
    STAGE_A_FROM(av0, 0);            // compiler waits av0 (vmcnt(8)) -> B(0) drained too
    asm volatile("s_waitcnt lgkmcnt(0)" ::: "memory");
    asm volatile("s_waitcnt vmcnt(8)" ::: "memory");   // keep av1 loads in flight
    __builtin_amdgcn_s_barrier();
    __builtin_amdgcn_sched_barrier(0);

    f32x4 acc[4][4];
    #pragma unroll
    for (int ht = 0; ht < 4; ht++)
        #pragma unroll
        for (int mt = 0; mt < 4; mt++)
            acc[ht][mt] = (f32x4){0.f, 0.f, 0.f, 0.f};

    const int kk = l >> 4, lm = l & 15;
    // per-lane LDS fragment offsets (in halves)
    const int aoff = kk * 896  + (hg * 64 + lm) * 8;   // + ht*128
    const int boff = kk * 2048 + (q * 64 + lm) * 8;    // + mt*128

    // step t: [B gll16(t+1)] [A loads(t+2)->loadSlot] [stage A(t+1) from stageSlot]
    //         [ds_read + MFMA from cur] [lgkm(0); vmcnt(8 keeps A(t+2)); s_barrier]
    #define STEP(t, cur, loadSlot, stageSlot)                                       \
        do {                                                                        \
            const int nb_ = (cur) ^ 1;                                              \
            if ((t) <= 14) STAGE_B((t) + 1, nb_);                                   \
            asm volatile("" ::: "memory");                                          \
            if ((t) <= 13) LOAD_A_TO(loadSlot, (t) + 2);                            \
            asm volatile("" ::: "memory");                                          \
            if ((t) <= 14) STAGE_A_FROM(stageSlot, nb_);                            \
            {                                                                       \
                const _Float16* Ab = &Abuf[cur][0][0][0];                           \
                const _Float16* Bb = &Bbuf[cur][0][0][0];                           \
                half8 afrag[4];                                                     \
                _Pragma("unroll")                                                   \
                for (int ht = 0; ht < 4; ht++)                                      \
                    if (ht < HT) afrag[ht] = *(const half8*)(Ab + aoff + ht * 128); \
                _Pragma("unroll")                                                   \
                for (int mt = 0; mt < 4; mt++) {                                    \
                    half8 bfrag = *(const half8*)(Bb + boff + mt * 128);            \
                    _Pragma("unroll")                                               \
                    for (int ht = 0; ht < 4; ht++)                                  \
                        if (ht < HT)                                                \
                            acc[ht][mt] = __builtin_amdgcn_mfma_f32_16x16x32_f16(   \
                                afrag[ht], bfrag, acc[ht][mt], 0, 0, 0);            \
                }                                                                   \
            }                                                                       \
            if ((t) < 15) {                                                         \
                asm volatile("s_waitcnt lgkmcnt(0)" ::: "memory");                  \
                if ((t) <= 13) asm volatile("s_waitcnt vmcnt(8)" ::: "memory");     \
                else           asm volatile("s_waitcnt vmcnt(0)" ::: "memory");     \
                __builtin_amdgcn_s_barrier();                                       \
                __builtin_amdgcn_sched_barrier(0);                                  \
            }                                                                       \
        } while (0)

    #pragma unroll
    for (int tt = 0; tt < 16; tt += 2) {
        STEP(tt,     0, av0, av1);   // load A(tt+2)->av0, stage A(tt+1) from av1
        STEP(tt + 1, 1, av1, av0);   // load A(tt+3)->av1, stage A(tt+2) from av0
    }

    #undef STEP
    #undef STAGE_B
    #undef LOAD_A_TO
    #undef STAGE_A_FROM

    // ---- img row norms (each row fully covered: 4 kg x 8 c x 16 steps)
    if (act) nrm_parts[p][hwl] = nrm;
    __syncthreads();
    if (tid < 112) {
        float v = 0.f;
        if (tid < 98)
            v = 1.0f / fmaxf(sqrtf(nrm_parts[0][tid] + nrm_parts[1][tid] +
                                   nrm_parts[2][tid] + nrm_parts[3][tid]), 1e-12f);
        rnorm_s[tid] = v;
    }
    __syncthreads();

    // ---- fused epilogue
    float mx[4], sw[4], swa[4];
    #pragma unroll
    for (int mt = 0; mt < 4; mt++) { mx[mt] = -1e30f; sw[mt] = 0.f; swa[mt] = 0.f; }
    float s1n = 0.f, s1d = 0.f, s2n = 0.f, s2d = 0.f;
    const int dmt = (n >> 4) & 3, dq = n >> 6, dl = n & 15;
    const bool isdiag = (q == dq) && (lm == dl);

    #pragma unroll
    for (int ht = 0; ht < 4; ht++) {
        if (ht < HT) {
            int rowb = hg * 64 + ht * 16 + (kk << 2);
            #pragma unroll
            for (int r = 0; r < 4; r++) {
                int row = rowb + r;
                float rn = rnorm_s[row];
                bool valid = row < 98;
                int hw = half * 98 + row;
                #pragma unroll
                for (int mt = 0; mt < 4; mt++) {
                    float a0 = acc[ht][mt][r] * rn;
                    if (valid) {
                        float wg = 1.0f / (1.0f + __expf((0.65f - a0) * (1.0f / 0.03f)));
                        mx[mt]  = fmaxf(mx[mt], a0);
                        sw[mt] += wg;
                        swa[mt] += wg * a0;
                        if (isdiag && mt == dmt) {
                            out[n * 196 + hw] = a0;                 // A
                            out[116224 + n * 196 + hw] = wg;        // Pos
                            float p2 = 1.0f / (1.0f + __expf((0.40f - a0) * (1.0f / 0.03f)));
                            float ng = 1.0f - p2;
                            out[166400 + n * 196 + hw] = ng;        // Neg
                            s1n += wg * a0; s1d += wg;
                            s2n += ng * a0; s2d += ng;
                        }
                    }
                }
            }
        }
    }

    // cross-lane reduce (lane groups 16 apart hold same m, different rows)
    #pragma unroll
    for (int mt = 0; mt < 4; mt++) {
        float m1 = mx[mt], v1 = sw[mt], v2 = swa[mt];
        m1 = fmaxf(m1, __shfl_xor(m1, 16, 64)); v1 += __shfl_xor(v1, 16, 64); v2 += __shfl_xor(v2, 16, 64);
        m1 = fmaxf(m1, __shfl_xor(m1, 32, 64)); v1 += __shfl_xor(v1, 32, 64); v2 += __shfl_xor(v2, 32, 64);
        if (l < 16) {
            int m = q * 64 + mt * 16 + l;
            red_max[hg][m] = m1; red_sw[hg][m] = v1; red_swa[hg][m] = v2;
        }
    }
    if (isdiag) {
        diag_parts[hg][kk][0] = s1n;
        diag_parts[hg][kk][1] = s1d;
        diag_parts[hg][kk][2] = s2n;
        diag_parts[hg][kk][3] = s2d;
    }
    __syncthreads();

    // ---- write per-(n,half) partials to workspace
    if (tid < 256) {
        int m = tid;
        int base = (n * 2 + half) * 256 + m;
        pmax[base] = fmaxf(red_max[0][m], red_max[1][m]);
        psw[base]  = red_sw[0][m] + red_sw[1][m];
        pswa[base] = red_swa[0][m] + red_swa[1][m];
    }
    if (tid < 4) {
        float s = 0.f;
        #pragma unroll
        for (int h2 = 0; h2 < 2; h2++)
            #pragma unroll
            for (int lg = 0; lg < 4; lg++)
                s += diag_parts[h2][lg][tid];
        pdiag[(n * 2 + half) * 4 + tid] = s;
    }
}

__global__ __launch_bounds__(256) void av_final(const float* __restrict__ pmax,
                                                const float* __restrict__ psw,
                                                const float* __restrict__ pswa,
                                                const float* __restrict__ pdiag,
                                                float* __restrict__ out) {
    int n = blockIdx.x, m = threadIdx.x;
    int b0 = (n * 2) * 256 + m, b1 = (n * 2 + 1) * 256 + m;
    float mx = fmaxf(pmax[b0], pmax[b1]);
    float sim = (pswa[b0] + pswa[b1]) / (psw[b0] + psw[b1]);
    if (m == n) sim *= -99.0f;
    out[50176 + n * 258 + 1 + m] = sim * RLT;
    out[216576 + n * 256 + m] = mx;
    if (m == n) {
        const float* d = pdiag + n * 8;   // [half0: 4][half1: 4]
        out[50176 + n * 258]       = ((d[0] + d[4]) / (d[1] + d[5])) * RLT;
        out[50176 + n * 258 + 257] = ((d[2] + d[6]) / (d[3] + d[7])) * RLT;
    }
}

extern "C" void kernel_launch(void* const* d_in, const int* in_sizes, int n_in,
                              void* d_out, int out_size, void* d_ws, size_t ws_size,
                              hipStream_t stream) {
    const float* img = (const float*)d_in[0];
    const float* aud = (const float*)d_in[1];
    float* out = (float*)d_out;

    _Float16* aud_pk = (_Float16*)d_ws;          // 256 KB region reserved
    float* wsf   = (float*)d_ws;
    float* pmax  = wsf + 65536;                  // after aud_pk (262144 B)
    float* psw   = pmax + 131072;                // 256*2*256
    float* pswa  = psw + 131072;
    float* pdiag = pswa + 131072;                // 256*2*4

    prep_aud_pk<<<256, 256, 0, stream>>>(aud, aud_pk);
    av_cnt<<<512, 512, 0, stream>>>(img, aud_pk, out, pmax, psw, pswa, pdiag);
    av_final<<<256, 256, 0, stream>>>(pmax, psw, pswa, pdiag, out);
}